// Round 8
// baseline (263.572 us; speedup 1.0000x reference)
//
#include <hip/hip_runtime.h>

// BaseAttention: B=2 H=16 S=2048 D=64, fp32 in/out.
// Round 12: T14 async-STAGE split, de-risked build.
//   Same structure as round 11 (never measured: 3x container-infra failures):
//   stage global->REGISTERS (barrier need not drain reg-dest loads), reg->LDS
//   write at top of NEXT iter (loads age a full iteration), double-buffered
//   frag-image LDS (every ds_read/write contiguous 16B/lane), ONE barrier/iter
//   draining only lgkmcnt.
//   De-risk deltas vs r11: launch_bounds(256,3) (relaxed reg cap); epilogue
//   exchange in SEPARATE __shared__ arrays (no aliasing of retired staging
//   buffers; 49.3KB LDS -> 3 blocks/CU = 12 waves/CU).
//   If this round also dies with "container failed twice": next round submits
//   the round-8 known-good kernel as an infra canary.
//   History: r8 LDS+gload_lds 2-wave = 75.7us (vmcnt(0)-drain bound, 6100
//   cyc/iter); r9 4-wave same drain = 81.5us; r10 no-LDS reg-stream = 90.6us
//   (2x L2 traffic). Carried: kh-split 4-wave blocks; Q pre-scaled
//   0.125*log2e; mask AND-words; P packed f16 pkrtz; l via 2 fdot2 chains;
//   PV mfma_f32_32x32x16_f16; cross-wave reduce at end only.

#define S_LEN 2048
#define D_DIM 64
#define N_KT 32
#define NBH 32
#define TILE_KV_SHORTS 8192            // 16 KB: [K frags 4096][V frags 4096]

typedef __attribute__((ext_vector_type(8))) short bf16x8;
typedef __attribute__((ext_vector_type(16))) float f32x16;
typedef __attribute__((ext_vector_type(2))) __fp16 fp16x2;
typedef unsigned int u32;
typedef unsigned long long u64;

#define C1 0.180336880111121f    // 0.125 * log2(e)
#define CM (-14426.9504088896f)  // -10000 * log2(e)  (fallback kernel only)

static __device__ __forceinline__ unsigned short f2bf(float f) {
  union { float f; unsigned u; } x; x.f = f;
  return (unsigned short)((x.u + 0x8000u) >> 16);
}
static __device__ __forceinline__ unsigned packbf(float lo, float hi) {
  union { float f; unsigned u; } a, b; a.f = lo; b.f = hi;
  return ((a.u + 0x8000u) >> 16) | ((b.u + 0x8000u) & 0xffff0000u);
}
static __device__ __forceinline__ f32x16 zero16() {
  f32x16 z;
#pragma unroll
  for (int i = 0; i < 16; ++i) z[i] = 0.f;
  return z;
}
static __device__ __forceinline__ unsigned pkh(float lo, float hi) {
  union { fp16x2 h; unsigned u; } x;
  x.h = __builtin_amdgcn_cvt_pkrtz(lo, hi);
  return x.u;
}

// ---- pre-pass: K,V -> combined per-tile fragment image ----
// per (bh,kt), 8192 shorts:
//   [0..4095]  K frags [kh(2)][ks(4)][hl(2)][col(32)][8]:
//              bf16( K[key=kh*32+col][d=ks*16+hl*8+j] )
//   [4096..]   V frags [kcHi(4)][hl(2)][b(2)][col(32)][8]:
//              f16( V[key=(2*kcHi+hl)*8+j][d=b*32+col] )
__global__ __launch_bounds__(256) void prep_kv(
    const float* __restrict__ k, const float* __restrict__ v,
    unsigned short* __restrict__ kvws) {
  const int kt = blockIdx.x, bh = blockIdx.y;
  const int t = threadIdx.x;
  __shared__ unsigned short Kr[64 * 72];
  __shared__ unsigned short Vr[64 * 72];
  const size_t goff = (size_t)bh * (S_LEN * D_DIM) + (size_t)kt * 64 * D_DIM;
  const float4* kg = (const float4*)(k + goff);
  const float4* vg = (const float4*)(v + goff);
#pragma unroll
  for (int j = 0; j < 4; ++j) {
    const int i = t + j * 256;
    const int row = i >> 4, c4 = i & 15;  // row = key, c4 = d-group (4 floats)
    const float4 x = kg[i];
    ushort4 w;
    w.x = f2bf(x.x); w.y = f2bf(x.y); w.z = f2bf(x.z); w.w = f2bf(x.w);
    *(ushort4*)&Kr[row * 72 + c4 * 4] = w;
    const float4 y = vg[i];
    const unsigned p01 = pkh(y.x, y.y), p23 = pkh(y.z, y.w);
    uint2 vv; vv.x = p01; vv.y = p23;
    *(uint2*)&Vr[row * 72 + c4 * 4] = vv;
  }
  __syncthreads();
  uint4* img = (uint4*)(kvws + (size_t)(bh * N_KT + kt) * TILE_KV_SHORTS);
  // K frags: 512 x 16B
  for (int c = t; c < 512; c += 256) {
    const int col = c & 31, hlc = (c >> 5) & 1, ks = (c >> 6) & 3, khc = c >> 8;
    img[c] = *(const uint4*)&Kr[(khc * 32 + col) * 72 + ks * 16 + hlc * 8];
  }
  // V frags (transpose gather): 512 x 16B at +512
  for (int c = t; c < 512; c += 256) {
    const int col = c & 31, b = (c >> 5) & 1, hlc = (c >> 6) & 1, kcHi = c >> 7;
    const int d = b * 32 + col, kk = (2 * kcHi + hlc) * 8;
    union { unsigned short s[8]; uint4 u; } o;
#pragma unroll
    for (int jj = 0; jj < 8; ++jj) o.s[jj] = Vr[(kk + jj) * 72 + d];
    img[512 + c] = o.u;
  }
}

// ---- pre-pass: mask -> u32 AND-words, fully coalesced ----
// One thread = one uint4 = words p=q4*4..q4*4+3 of (row,hl,kt).
// word p=kb*8+g*2+h covers keys j=32kb+8g+4hl+2h+{0,1}; ==0 -> keep (0xFFFF).
__global__ __launch_bounds__(256) void prep_mask(
    const int* __restrict__ mask, u32* __restrict__ mw) {
  const int gt = blockIdx.x * 256 + threadIdx.x;  // 524288 total
  const int q4 = gt & 3;
  const int kt = (gt >> 2) & 31;
  const int hl = (gt >> 7) & 1;
  const int row = gt >> 8;
  const int j0 = kt * 64 + 32 * (q4 >> 1) + 16 * (q4 & 1) + 4 * hl;
  const int* mr = mask + (size_t)row * S_LEN;
  const int4 a = *(const int4*)(mr + j0);
  const int4 b = *(const int4*)(mr + j0 + 8);
  uint4 w;
  w.x = (a.x == 0 ? 0x0000FFFFu : 0u) | (a.y == 0 ? 0xFFFF0000u : 0u);
  w.y = (a.z == 0 ? 0x0000FFFFu : 0u) | (a.w == 0 ? 0xFFFF0000u : 0u);
  w.z = (b.x == 0 ? 0x0000FFFFu : 0u) | (b.y == 0 ? 0xFFFF0000u : 0u);
  w.w = (b.z == 0 ? 0x0000FFFFu : 0u) | (b.w == 0 ? 0xFFFF0000u : 0u);
  *(uint4*)&mw[((size_t)(row * 2 + hl) * N_KT + kt) * 16 + q4 * 4] = w;
}

// ---- main: flash attention, async-STAGE split, 1 barrier/iter ----
__global__ __launch_bounds__(256, 3) void attn_fwd(
    const float* __restrict__ q, const unsigned short* __restrict__ kvws,
    const u32* __restrict__ mw, float* __restrict__ out) {
  const int qt = blockIdx.x;  // 0..31 (64 q rows per block)
  const int bh = blockIdx.y;  // 0..31
  const size_t hoff = (size_t)bh * (S_LEN * D_DIM);

  __shared__ unsigned short sbuf[2][TILE_KV_SHORTS];  // 2 x 16 KB staging
  __shared__ float xb[64 * 68];                       // epilogue O exchange
  __shared__ float lb[64];                            // epilogue l exchange

  const int t = threadIdx.x;
  const int wave = t >> 6;
  const int lane = t & 63;
  const int col = lane & 31;
  const int hl = lane >> 5;
  const int qh = wave >> 1;  // q half
  const int kh = wave & 1;   // key half of each tile

  const int qg = qt * 64 + qh * 32 + col;

  // Q^T B-fragments, PRE-SCALED by C1
  bf16x8 bQ[4];
  {
    const float* qrow = q + hoff + (size_t)qg * D_DIM;
#pragma unroll
    for (int ks = 0; ks < 4; ++ks) {
      const float4 x0 = *(const float4*)(qrow + ks * 16 + hl * 8);
      const float4 x1 = *(const float4*)(qrow + ks * 16 + hl * 8 + 4);
      union { bf16x8 v; unsigned d[4]; } u;
      u.d[0] = packbf(x0.x * C1, x0.y * C1);
      u.d[1] = packbf(x0.z * C1, x0.w * C1);
      u.d[2] = packbf(x1.x * C1, x1.y * C1);
      u.d[3] = packbf(x1.z * C1, x1.w * C1);
      bQ[ks] = u.v;
    }
  }

  f32x16 oT0 = zero16(), oT1 = zero16();
  float lacc0 = 0.f, lacc1 = 0.f;
  const uint4* mrow = (const uint4*)(mw + (size_t)(qg * 2 + hl) * N_KT * 16);
  const uint4* kvt = (const uint4*)(kvws + (size_t)bh * N_KT * TILE_KV_SHORTS);

#if __has_builtin(__builtin_amdgcn_fdot2)
  const fp16x2 ones2 = {(__fp16)1.0f, (__fp16)1.0f};
#endif

  // prologue: tile 0 -> regs -> LDS buf0; tile 1 -> regs
  uint4 st[4];
#pragma unroll
  for (int i = 0; i < 4; ++i) st[i] = kvt[t + i * 256];
  {
    uint4* lw = (uint4*)&sbuf[0][0];
#pragma unroll
    for (int i = 0; i < 4; ++i) lw[t + i * 256] = st[i];
  }
#pragma unroll
  for (int i = 0; i < 4; ++i) st[i] = kvt[1024 + t + i * 256];
  __syncthreads();

  for (int kt = 0; kt < N_KT; ++kt) {
    const int p = kt & 1;
    // write staged tile kt+1 (regs loaded last iter; latency long aged)
    if (kt + 1 < N_KT) {
      uint4* lw = (uint4*)&sbuf[p ^ 1][0];
#pragma unroll
      for (int i = 0; i < 4; ++i) lw[t + i * 256] = st[i];
    }
    // issue loads for tile kt+2 -> regs (stay in flight across the barrier)
    if (kt + 2 < N_KT) {
      const uint4* gg = kvt + (size_t)(kt + 2) * 1024;
#pragma unroll
      for (int i = 0; i < 4; ++i) st[i] = gg[t + i * 256];
    }

    // mask AND-words for this tile & key half (issue early)
    const uint4 mq0 = mrow[kt * 4 + kh * 2 + 0];
    const uint4 mq1 = mrow[kt * 4 + kh * 2 + 1];

    const unsigned short* Kb = &sbuf[p][0];
    const unsigned short* Vb = &sbuf[p][4096];

    // S^T = K Q^T : 32-key half x K=64 (pre-scaled via Q)
    f32x16 sT = zero16();
#pragma unroll
    for (int ks = 0; ks < 4; ++ks) {
      const bf16x8 aK =
          *(const bf16x8*)&Kb[kh * 2048 + ks * 512 + hl * 256 + col * 8];
      sT = __builtin_amdgcn_mfma_f32_32x32x16_bf16(aK, bQ[ks], sT, 0, 0, 0);
    }

    const u32 mwv[8] = {mq0.x, mq0.y, mq0.z, mq0.w,
                        mq1.x, mq1.y, mq1.z, mq1.w};
    unsigned pw[8];
#pragma unroll
    for (int g2 = 0; g2 < 4; ++g2) {
      const float e0 = __builtin_amdgcn_exp2f(sT[g2 * 4 + 0]);
      const float e1 = __builtin_amdgcn_exp2f(sT[g2 * 4 + 1]);
      const float e2 = __builtin_amdgcn_exp2f(sT[g2 * 4 + 2]);
      const float e3 = __builtin_amdgcn_exp2f(sT[g2 * 4 + 3]);
#if __has_builtin(__builtin_amdgcn_fdot2)
      const unsigned w0 = pkh(e0, e1) & mwv[g2 * 2 + 0];
      const unsigned w1 = pkh(e2, e3) & mwv[g2 * 2 + 1];
      pw[g2 * 2 + 0] = w0;
      pw[g2 * 2 + 1] = w1;
      union { unsigned u; fp16x2 h; } c0, c1;
      c0.u = w0; c1.u = w1;
      lacc0 = __builtin_amdgcn_fdot2(c0.h, ones2, lacc0, false);
      lacc1 = __builtin_amdgcn_fdot2(c1.h, ones2, lacc1, false);
#else
      const u32 mlo = mwv[g2 * 2 + 0], mhi = mwv[g2 * 2 + 1];
      const float e0m = (mlo & 0xFFFFu) ? e0 : 0.f;
      const float e1m = (mlo >> 16) ? e1 : 0.f;
      const float e2m = (mhi & 0xFFFFu) ? e2 : 0.f;
      const float e3m = (mhi >> 16) ? e3 : 0.f;
      pw[g2 * 2 + 0] = pkh(e0m, e1m);
      pw[g2 * 2 + 1] = pkh(e2m, e3m);
      lacc0 += e0m + e1m;
      lacc1 += e2m + e3m;
#endif
    }

    // O^T += Vt * P^T
#pragma unroll
    for (int ks2 = 0; ks2 < 2; ++ks2) {
      const unsigned d0 = pw[4 * ks2 + 0], d1 = pw[4 * ks2 + 1];
      const unsigned d2 = pw[4 * ks2 + 2], d3 = pw[4 * ks2 + 3];
      const unsigned s0 = hl ? d0 : d2;
      const unsigned s1 = hl ? d1 : d3;
      const unsigned r0 = (unsigned)__shfl_xor((int)s0, 32);
      const unsigned r1 = (unsigned)__shfl_xor((int)s1, 32);
      union { bf16x8 v; unsigned d[4]; } pf;
      pf.d[0] = hl ? r0 : d0;
      pf.d[1] = hl ? r1 : d1;
      pf.d[2] = hl ? d2 : r0;
      pf.d[3] = hl ? d3 : r1;
      const int kcHi = kh * 2 + ks2;
      const bf16x8 aV0 =
          *(const bf16x8*)&Vb[kcHi * 1024 + hl * 512 + 0 * 256 + col * 8];
      const bf16x8 aV1 =
          *(const bf16x8*)&Vb[kcHi * 1024 + hl * 512 + 1 * 256 + col * 8];
      oT0 = __builtin_amdgcn_mfma_f32_32x32x16_f16(aV0, pf.v, oT0, 0, 0, 0);
      oT1 = __builtin_amdgcn_mfma_f32_32x32x16_f16(aV1, pf.v, oT1, 0, 0, 0);
    }

    __syncthreads();  // only lgkmcnt to drain (reg-dest global loads fly on)
  }

  // ---- cross-wave key-half reduction via dedicated LDS arrays ----
  {
    const float lsum = lacc0 + lacc1;
    const float l2 = lsum + __shfl_xor(lsum, 32);
    float* xr = xb + (size_t)(qh * 32 + col) * 68;  // stride 68: bank spread
    if (kh) {
#pragma unroll
      for (int rg = 0; rg < 4; ++rg) {
        float4 w0, w1;
        w0.x = oT0[rg * 4 + 0]; w0.y = oT0[rg * 4 + 1];
        w0.z = oT0[rg * 4 + 2]; w0.w = oT0[rg * 4 + 3];
        w1.x = oT1[rg * 4 + 0]; w1.y = oT1[rg * 4 + 1];
        w1.z = oT1[rg * 4 + 2]; w1.w = oT1[rg * 4 + 3];
        *(float4*)(xr + 8 * rg + 4 * hl) = w0;
        *(float4*)(xr + 32 + 8 * rg + 4 * hl) = w1;
      }
      if (!hl) lb[qh * 32 + col] = l2;
    }
    __syncthreads();
    if (!kh) {
      const float inv = 1.0f / (l2 + lb[qh * 32 + col]);
      float* orow = out + hoff + (size_t)qg * D_DIM;
#pragma unroll
      for (int rg = 0; rg < 4; ++rg) {
        const float4 a0 = *(const float4*)(xr + 8 * rg + 4 * hl);
        const float4 a1 = *(const float4*)(xr + 32 + 8 * rg + 4 * hl);
        float4 w0, w1;
        w0.x = (oT0[rg * 4 + 0] + a0.x) * inv;
        w0.y = (oT0[rg * 4 + 1] + a0.y) * inv;
        w0.z = (oT0[rg * 4 + 2] + a0.z) * inv;
        w0.w = (oT0[rg * 4 + 3] + a0.w) * inv;
        w1.x = (oT1[rg * 4 + 0] + a1.x) * inv;
        w1.y = (oT1[rg * 4 + 1] + a1.y) * inv;
        w1.z = (oT1[rg * 4 + 2] + a1.z) * inv;
        w1.w = (oT1[rg * 4 + 3] + a1.w) * inv;
        *(float4*)(orow + 8 * rg + 4 * hl) = w0;
        *(float4*)(orow + 32 + 8 * rg + 4 * hl) = w1;
      }
    }
  }
}

// ---- fallback (round-4 kernel, self-staging) if ws is too small ----
#define LDK 72
#define LDV 72
__global__ __launch_bounds__(256, 2) void attn_fwd_self(
    const float* __restrict__ q, const float* __restrict__ k,
    const float* __restrict__ v, const int* __restrict__ mask,
    float* __restrict__ out) {
  const int qt = blockIdx.x;
  const int bh = blockIdx.y;
  const size_t hoff = (size_t)bh * (S_LEN * D_DIM);
  __shared__ unsigned short Ks[64 * LDK];
  __shared__ unsigned short Vt[64 * LDV];
  const int t = threadIdx.x;
  const int wave = t >> 6;
  const int lane = t & 63;
  const int col = lane & 31;
  const int hl = lane >> 5;
  const int sw = col >> 2;
  const int qg = qt * 128 + wave * 32 + col;
  bf16x8 bQ[4];
  {
    const float* qrow = q + hoff + (size_t)qg * D_DIM;
#pragma unroll
    for (int ks = 0; ks < 4; ++ks) {
      const float4 x0 = *(const float4*)(qrow + ks * 16 + hl * 8);
      const float4 x1 = *(const float4*)(qrow + ks * 16 + hl * 8 + 4);
      union { bf16x8 v; unsigned d[4]; } u;
      u.d[0] = packbf(x0.x, x0.y);
      u.d[1] = packbf(x0.z, x0.w);
      u.d[2] = packbf(x1.x, x1.y);
      u.d[3] = packbf(x1.z, x1.w);
      bQ[ks] = u.v;
    }
  }
  float4 pk[4], pv[4];
  {
    const float4* kg = (const float4*)(k + hoff);
    const float4* vg = (const float4*)(v + hoff);
#pragma unroll
    for (int j = 0; j < 4; ++j) { pk[j] = kg[t + j * 256]; pv[j] = vg[t + j * 256]; }
  }
  f32x16 oT0 = zero16(), oT1 = zero16();
  float lacc = 0.f;
  const int* mrow = mask + (size_t)qg * S_LEN;
  for (int kt = 0; kt < N_KT; ++kt) {
    __syncthreads();
#pragma unroll
    for (int j = 0; j < 4; ++j) {
      const int i = t + j * 256;
      const int row = i >> 4, c4 = i & 15;
      ushort4 w;
      w.x = f2bf(pk[j].x); w.y = f2bf(pk[j].y);
      w.z = f2bf(pk[j].z); w.w = f2bf(pk[j].w);
      *(ushort4*)&Ks[row * LDK + c4 * 4] = w;
      const int swc = 8 * (((row >> 3) + c4) & 7) + (row & 7);
      Vt[(4 * c4 + 0) * LDV + swc] = f2bf(pv[j].x);
      Vt[(4 * c4 + 1) * LDV + swc] = f2bf(pv[j].y);
      Vt[(4 * c4 + 2) * LDV + swc] = f2bf(pv[j].z);
      Vt[(4 * c4 + 3) * LDV + swc] = f2bf(pv[j].w);
    }
    __syncthreads();
    if (kt + 1 < N_KT) {
      const float4* kg = (const float4*)(k + hoff + (size_t)(kt + 1) * 64 * D_DIM);
      const float4* vg = (const float4*)(v + hoff + (size_t)(kt + 1) * 64 * D_DIM);
#pragma unroll
      for (int j = 0; j < 4; ++j) { pk[j] = kg[t + j * 256]; pv[j] = vg[t + j * 256]; }
    }
    int4 mq[2][4];
#pragma unroll
    for (int kb = 0; kb < 2; ++kb)
#pragma unroll
      for (int g = 0; g < 4; ++g)
        mq[kb][g] = *(const int4*)(mrow + kt * 64 + kb * 32 + g * 8 + hl * 4);
    f32x16 sT0 = zero16(), sT1 = zero16();
#pragma unroll
    for (int ks = 0; ks < 4; ++ks) {
      const bf16x8 aK0 = *(const bf16x8*)&Ks[col * LDK + ks * 16 + hl * 8];
      const bf16x8 aK1 = *(const bf16x8*)&Ks[(32 + col) * LDK + ks * 16 + hl * 8];
      sT0 = __builtin_amdgcn_mfma_f32_32x32x16_bf16(aK0, bQ[ks], sT0, 0, 0, 0);
      sT1 = __builtin_amdgcn_mfma_f32_32x32x16_bf16(aK1, bQ[ks], sT1, 0, 0, 0);
    }
    unsigned pw[2][8];
#pragma unroll
    for (int kb = 0; kb < 2; ++kb) {
      const f32x16 sT = kb ? sT1 : sT0;
      float e[16];
#pragma unroll
      for (int g = 0; g < 4; ++g) {
        const int4 mv = mq[kb][g];
        const int* mvp = &mv.x;
#pragma unroll
        for (int r3 = 0; r3 < 4; ++r3) {
          const int reg = g * 4 + r3;
          const float bias = mvp[r3] ? CM : 0.0f;
          const float ev = __builtin_amdgcn_exp2f(fmaf(sT[reg], C1, bias));
          e[reg] = ev;
          lacc += ev;
        }
        pw[kb][g * 2 + 0] = packbf(e[g * 4 + 0], e[g * 4 + 1]);
        pw[kb][g * 2 + 1] = packbf(e[g * 4 + 2], e[g * 4 + 3]);
      }
    }
#pragma unroll
    for (int ks = 0; ks < 4; ++ks) {
      const int kb = ks >> 1, h = ks & 1;
      const unsigned d0 = pw[kb][4 * h + 0], d1 = pw[kb][4 * h + 1];
      const unsigned d2 = pw[kb][4 * h + 2], d3 = pw[kb][4 * h + 3];
      const unsigned s0 = hl ? d0 : d2;
      const unsigned s1 = hl ? d1 : d3;
      const unsigned r0 = (unsigned)__shfl_xor((int)s0, 32);
      const unsigned r1 = (unsigned)__shfl_xor((int)s1, 32);
      union { bf16x8 v; unsigned d[4]; } pf;
      pf.d[0] = hl ? r0 : d0;
      pf.d[1] = hl ? r1 : d1;
      pf.d[2] = hl ? d2 : r0;
      pf.d[3] = hl ? d3 : r1;
      const int cpr = 8 * (((2 * ks + hl) + sw) & 7);
      const bf16x8 aV0 = *(const bf16x8*)&Vt[col * LDV + cpr];
      const bf16x8 aV1 = *(const bf16x8*)&Vt[(32 + col) * LDV + cpr];
      oT0 = __builtin_amdgcn_mfma_f32_32x32x16_bf16(aV0, pf.v, oT0, 0, 0, 0);
      oT1 = __builtin_amdgcn_mfma_f32_32x32x16_bf16(aV1, pf.v, oT1, 0, 0, 0);
    }
  }
  const float ltot = lacc + __shfl_xor(lacc, 32);
  const float inv = 1.0f / ltot;
  float* orow = out + hoff + (size_t)qg * D_DIM;
#pragma unroll
  for (int rg = 0; rg < 4; ++rg) {
    float4 w0, w1;
    w0.x = oT0[rg * 4 + 0] * inv; w0.y = oT0[rg * 4 + 1] * inv;
    w0.z = oT0[rg * 4 + 2] * inv; w0.w = oT0[rg * 4 + 3] * inv;
    w1.x = oT1[rg * 4 + 0] * inv; w1.y = oT1[rg * 4 + 1] * inv;
    w1.z = oT1[rg * 4 + 2] * inv; w1.w = oT1[rg * 4 + 3] * inv;
    *(float4*)(orow + 8 * rg + 4 * hl) = w0;
    *(float4*)(orow + 32 + 8 * rg + 4 * hl) = w1;
  }
}

extern "C" void kernel_launch(void* const* d_in, const int* in_sizes, int n_in,
                              void* d_out, int out_size, void* d_ws, size_t ws_size,
                              hipStream_t stream) {
  const float* q = (const float*)d_in[0];
  const float* k = (const float*)d_in[1];
  const float* v = (const float*)d_in[2];
  const int* mask = (const int*)d_in[3];
  float* out = (float*)d_out;

  const size_t kv_shorts = (size_t)NBH * N_KT * TILE_KV_SHORTS;
  const size_t mw_words = (size_t)S_LEN * 2 * N_KT * 16;  // u32 count
  const size_t need = kv_shorts * sizeof(unsigned short) + mw_words * 4;

  if (ws_size >= need) {
    unsigned short* kvws = (unsigned short*)d_ws;
    u32* mwp = (u32*)(kvws + kv_shorts);
    prep_kv<<<dim3(N_KT, NBH), dim3(256), 0, stream>>>(k, v, kvws);
    prep_mask<<<dim3((S_LEN * 2 * N_KT * 4) / 256), dim3(256), 0, stream>>>(mask, mwp);
    attn_fwd<<<dim3(S_LEN / 64, NBH), dim3(256), 0, stream>>>(q, kvws, mwp, out);
  } else {
    attn_fwd_self<<<dim3(S_LEN / 128, NBH), dim3(256), 0, stream>>>(q, k, v, mask, out);
  }
}

// Round 9
// 167.265 us; speedup vs baseline: 1.5758x; 1.5758x over previous
//
#include <hip/hip_runtime.h>

// BaseAttention: B=2 H=16 S=2048 D=64, fp32 in/out.
// Round 13: counted-vmcnt pipeline (T3/T4) on the proven gload_lds base.
//   r12 post-mortem: reg-staging spilled to scratch (WRITE_SIZE 16->168 MB,
//   attn 175us). r8 (gload_lds + __syncthreads drain) remains best at 75.7us
//   with 6100 cyc/iter = vmcnt(0) drain. Fix per m201 template: raw s_barrier
//   + counted s_waitcnt vmcnt(5) (never 0 mid-loop) so next-tile DMAs stay in
//   flight across barriers. Image padded to 20x1KB segs -> each of 4 waves
//   stages exactly 5 segs/tile (uniform vmcnt). Mask loads = pinned inline-asm
//   global_load_dwordx4 issued BEFORE the stage cluster => per-iter vmem order
//   [ml(kt+1) x2, stage(kt+2) x5]; entry vmcnt(5) => tile kt + mask(kt) done.
//   sched_barrier(0) after every fence (rule 18). 2 raw barriers/iter; exit
//   barrier after lgkmcnt(0) orders reads-done before re-staging same buffer.
//   Carried (all HW-validated): kh-split 4-wave blocks (r9), K layout pitch-72
//   + V swizzle/cpr (r8), prep_mask AND-words (r12), fdot2 l (r10/r12),
//   Q pre-scaled 0.125*log2e, P packed f16 pkrtz, PV mfma_32x32x16_f16,
//   cross-wave reduce via LDS alias at end (r9/r12).

#define S_LEN 2048
#define D_DIM 64
#define N_KT 32
#define NBH 32
#define TILE_SEGS 20
#define TILE_SHORTS_P (TILE_SEGS * 512)   // 10240 shorts = 20 KB (18 used + 2 pad)
#define K_SHORTS 4608                     // 64*72
#define SEG_U32 256                       // 1024 B per seg (64 lanes x 16 B)

typedef __attribute__((ext_vector_type(8))) short bf16x8;
typedef __attribute__((ext_vector_type(16))) float f32x16;
typedef __attribute__((ext_vector_type(2))) __fp16 fp16x2;
typedef unsigned int u32;

#define C1 0.180336880111121f    // 0.125 * log2(e)
#define CM (-14426.9504088896f)  // -10000 * log2(e)  (fallback kernel only)

static __device__ __forceinline__ unsigned short f2bf(float f) {
  union { float f; unsigned u; } x; x.f = f;
  return (unsigned short)((x.u + 0x8000u) >> 16);
}
static __device__ __forceinline__ unsigned packbf(float lo, float hi) {
  union { float f; unsigned u; } a, b; a.f = lo; b.f = hi;
  return ((a.u + 0x8000u) >> 16) | ((b.u + 0x8000u) & 0xffff0000u);
}
static __device__ __forceinline__ f32x16 zero16() {
  f32x16 z;
#pragma unroll
  for (int i = 0; i < 16; ++i) z[i] = 0.f;
  return z;
}
static __device__ __forceinline__ void dma16(const u32* g, u32* l) {
  __builtin_amdgcn_global_load_lds(
      (const __attribute__((address_space(1))) u32*)g,
      (__attribute__((address_space(3))) u32*)l, 16, 0, 0);
}
static __device__ __forceinline__ unsigned pkh(float lo, float hi) {
  union { fp16x2 h; unsigned u; } x;
  x.h = __builtin_amdgcn_cvt_pkrtz(lo, hi);
  return x.u;
}

// ---- pre-pass: K,V -> per-tile image, 20-seg stride ----
// per (bh,kt), 10240 shorts: [0..4607] K [key][d] pitch 72 (bf16);
// [4608..9215] V swizzled-transpose (f16, r8 layout); [9216..] pad.
__global__ __launch_bounds__(256) void prep_kv(
    const float* __restrict__ k, const float* __restrict__ v,
    unsigned short* __restrict__ kvws) {
  const int kt = blockIdx.x, bh = blockIdx.y;
  const int t = threadIdx.x;
  __shared__ unsigned short Vt[K_SHORTS];
  const size_t goff = (size_t)bh * (S_LEN * D_DIM) + (size_t)kt * 64 * D_DIM;
  const float4* kg = (const float4*)(k + goff);
  const float4* vg = (const float4*)(v + goff);
  unsigned short* kimg = kvws + (size_t)(bh * N_KT + kt) * TILE_SHORTS_P;
#pragma unroll
  for (int j = 0; j < 4; ++j) {
    const int i = t + j * 256;
    const int row = i >> 4, c4 = i & 15;  // row = key, c4 = d-group
    const float4 x = kg[i];
    ushort4 w;
    w.x = f2bf(x.x); w.y = f2bf(x.y); w.z = f2bf(x.z); w.w = f2bf(x.w);
    *(ushort4*)&kimg[row * 72 + c4 * 4] = w;
    const float4 y = vg[i];
    const int swc = 8 * (((row >> 3) + c4) & 7) + (row & 7);
    const unsigned p01 = pkh(y.x, y.y);
    const unsigned p23 = pkh(y.z, y.w);
    Vt[(4 * c4 + 0) * 72 + swc] = (unsigned short)(p01 & 0xffff);
    Vt[(4 * c4 + 1) * 72 + swc] = (unsigned short)(p01 >> 16);
    Vt[(4 * c4 + 2) * 72 + swc] = (unsigned short)(p23 & 0xffff);
    Vt[(4 * c4 + 3) * 72 + swc] = (unsigned short)(p23 >> 16);
  }
  __syncthreads();
  uint4* vimg = (uint4*)(kimg + K_SHORTS);
  const uint4* lv = (const uint4*)Vt;
  for (int i = t; i < K_SHORTS / 8; i += 256) vimg[i] = lv[i];
}

// ---- pre-pass: mask -> u32 AND-words (validated r12) ----
__global__ __launch_bounds__(256) void prep_mask(
    const int* __restrict__ mask, u32* __restrict__ mw) {
  const int gt = blockIdx.x * 256 + threadIdx.x;  // 524288 total
  const int q4 = gt & 3;
  const int kt = (gt >> 2) & 31;
  const int hl = (gt >> 7) & 1;
  const int row = gt >> 8;
  const int j0 = kt * 64 + 32 * (q4 >> 1) + 16 * (q4 & 1) + 4 * hl;
  const int* mr = mask + (size_t)row * S_LEN;
  const int4 a = *(const int4*)(mr + j0);
  const int4 b = *(const int4*)(mr + j0 + 8);
  uint4 w;
  w.x = (a.x == 0 ? 0x0000FFFFu : 0u) | (a.y == 0 ? 0xFFFF0000u : 0u);
  w.y = (a.z == 0 ? 0x0000FFFFu : 0u) | (a.w == 0 ? 0xFFFF0000u : 0u);
  w.z = (b.x == 0 ? 0x0000FFFFu : 0u) | (b.y == 0 ? 0xFFFF0000u : 0u);
  w.w = (b.z == 0 ? 0x0000FFFFu : 0u) | (b.w == 0 ? 0xFFFF0000u : 0u);
  *(uint4*)&mw[((size_t)(row * 2 + hl) * N_KT + kt) * 16 + q4 * 4] = w;
}

// ---- main: flash attention, counted-vmcnt DMA pipeline ----
__global__ __launch_bounds__(256, 4) void attn_fwd(
    const float* __restrict__ q, const unsigned short* __restrict__ kvws,
    const u32* __restrict__ mw, float* __restrict__ out) {
  const int qt = blockIdx.x;  // 0..31 (64 q rows per block)
  const int bh = blockIdx.y;  // 0..31
  const size_t hoff = (size_t)bh * (S_LEN * D_DIM);

  __shared__ unsigned short sbuf[2][TILE_SHORTS_P];  // 2 x 20 KB

  const int t = threadIdx.x;
  const int wave = t >> 6;
  const int lane = t & 63;
  const int col = lane & 31;
  const int hl = lane >> 5;
  const int sw = col >> 2;
  const int qh = wave >> 1;  // q half
  const int kh = wave & 1;   // key half of each tile
  const int qg = qt * 64 + qh * 32 + col;

  // Q^T B-fragments, PRE-SCALED by C1
  bf16x8 bQ[4];
  {
    const float* qrow = q + hoff + (size_t)qg * D_DIM;
#pragma unroll
    for (int ks = 0; ks < 4; ++ks) {
      const float4 x0 = *(const float4*)(qrow + ks * 16 + hl * 8);
      const float4 x1 = *(const float4*)(qrow + ks * 16 + hl * 8 + 4);
      union { bf16x8 v; unsigned d[4]; } u;
      u.d[0] = packbf(x0.x * C1, x0.y * C1);
      u.d[1] = packbf(x0.z * C1, x0.w * C1);
      u.d[2] = packbf(x1.x * C1, x1.y * C1);
      u.d[3] = packbf(x1.z * C1, x1.w * C1);
      bQ[ks] = u.v;
    }
  }

  f32x16 oT0 = zero16(), oT1 = zero16();
  float lacc0 = 0.f, lacc1 = 0.f;
  const uint4* mrow = (const uint4*)(mw + (size_t)(qg * 2 + hl) * N_KT * 16);
  const u32* img = (const u32*)(kvws + (size_t)bh * N_KT * TILE_SHORTS_P);
  const int seg0 = wave * 5;  // this wave's 5 segments of each 20-seg tile

#if __has_builtin(__builtin_amdgcn_fdot2)
  const fp16x2 ones2 = {(__fp16)1.0f, (__fp16)1.0f};
#endif

  uint4 mq0, mq1;
  // prologue vmem order (per wave): ml(0) x2, stage(0) x5, stage(1) x5.
  {
    const uint4* mp = mrow + kh * 2;
    asm volatile("global_load_dwordx4 %0, %2, off\n\t"
                 "global_load_dwordx4 %1, %3, off"
                 : "=&v"(mq0), "=&v"(mq1)
                 : "v"(mp), "v"(mp + 1)
                 : "memory");
  }
#pragma unroll
  for (int s = 0; s < 5; ++s)
    dma16(img + (size_t)(seg0 + s) * SEG_U32 + lane * 4,
          (u32*)&sbuf[0][0] + (seg0 + s) * SEG_U32);
#pragma unroll
  for (int s = 0; s < 5; ++s)
    dma16(img + (size_t)(TILE_SEGS + seg0 + s) * SEG_U32 + lane * 4,
          (u32*)&sbuf[1][0] + (seg0 + s) * SEG_U32);

  for (int kt = 0; kt < N_KT; ++kt) {
    const int p = kt & 1;
    // entry: wait own-wave DMAs for tile kt (+ mask kt); tile kt+1 stays in flight
    if (kt < N_KT - 1) {
      asm volatile("s_waitcnt vmcnt(5)" ::: "memory");
    } else {
      asm volatile("s_waitcnt vmcnt(0)" ::: "memory");
    }
    __builtin_amdgcn_s_barrier();
    __builtin_amdgcn_sched_barrier(0);

    const unsigned short* Ksb = &sbuf[p][0];
    const unsigned short* Vtb = &sbuf[p][K_SHORTS];
    const u32 mwv[8] = {mq0.x, mq0.y, mq0.z, mq0.w,
                        mq1.x, mq1.y, mq1.z, mq1.w};

    // S^T = K Q^T : this wave's 32-key half x K=64 (pre-scaled via Q)
    f32x16 sT = zero16();
#pragma unroll
    for (int ks = 0; ks < 4; ++ks) {
      const bf16x8 aK =
          *(const bf16x8*)&Ksb[(kh * 32 + col) * 72 + ks * 16 + hl * 8];
      sT = __builtin_amdgcn_mfma_f32_32x32x16_bf16(aK, bQ[ks], sT, 0, 0, 0);
    }

    // p = exp2(s), pack f16 (pkrtz), mask with AND-words, l via fdot2
    unsigned pw[8];
#pragma unroll
    for (int g2 = 0; g2 < 4; ++g2) {
      const float e0 = __builtin_amdgcn_exp2f(sT[g2 * 4 + 0]);
      const float e1 = __builtin_amdgcn_exp2f(sT[g2 * 4 + 1]);
      const float e2 = __builtin_amdgcn_exp2f(sT[g2 * 4 + 2]);
      const float e3 = __builtin_amdgcn_exp2f(sT[g2 * 4 + 3]);
#if __has_builtin(__builtin_amdgcn_fdot2)
      const unsigned w0 = pkh(e0, e1) & mwv[g2 * 2 + 0];
      const unsigned w1 = pkh(e2, e3) & mwv[g2 * 2 + 1];
      pw[g2 * 2 + 0] = w0;
      pw[g2 * 2 + 1] = w1;
      union { unsigned u; fp16x2 h; } c0, c1;
      c0.u = w0; c1.u = w1;
      lacc0 = __builtin_amdgcn_fdot2(c0.h, ones2, lacc0, false);
      lacc1 = __builtin_amdgcn_fdot2(c1.h, ones2, lacc1, false);
#else
      const u32 mlo = mwv[g2 * 2 + 0], mhi = mwv[g2 * 2 + 1];
      const float e0m = (mlo & 0xFFFFu) ? e0 : 0.f;
      const float e1m = (mlo >> 16) ? e1 : 0.f;
      const float e2m = (mhi & 0xFFFFu) ? e2 : 0.f;
      const float e3m = (mhi >> 16) ? e3 : 0.f;
      pw[g2 * 2 + 0] = pkh(e0m, e1m);
      pw[g2 * 2 + 1] = pkh(e2m, e3m);
      lacc0 += e0m + e1m;
      lacc1 += e2m + e3m;
#endif
    }

    // O^T += Vt * P^T (r8's swizzled V layout, cpr rotation)
#pragma unroll
    for (int ks2 = 0; ks2 < 2; ++ks2) {
      const unsigned d0 = pw[4 * ks2 + 0], d1 = pw[4 * ks2 + 1];
      const unsigned d2 = pw[4 * ks2 + 2], d3 = pw[4 * ks2 + 3];
      const unsigned s0 = hl ? d0 : d2;
      const unsigned s1 = hl ? d1 : d3;
      const unsigned r0 = (unsigned)__shfl_xor((int)s0, 32);
      const unsigned r1 = (unsigned)__shfl_xor((int)s1, 32);
      union { bf16x8 v; unsigned d[4]; } pf;
      pf.d[0] = hl ? r0 : d0;
      pf.d[1] = hl ? r1 : d1;
      pf.d[2] = hl ? d2 : r0;
      pf.d[3] = hl ? d3 : r1;
      const int cpr = 8 * (((4 * kh + 2 * ks2 + hl) + sw) & 7);
      const bf16x8 aV0 = *(const bf16x8*)&Vtb[col * 72 + cpr];
      const bf16x8 aV1 = *(const bf16x8*)&Vtb[(32 + col) * 72 + cpr];
      oT0 = __builtin_amdgcn_mfma_f32_32x32x16_f16(aV0, pf.v, oT0, 0, 0, 0);
      oT1 = __builtin_amdgcn_mfma_f32_32x32x16_f16(aV1, pf.v, oT1, 0, 0, 0);
    }

    // exit: reads of buf[p] done -> allow re-staging it; masks BEFORE dmas
    if (kt < N_KT - 1) {
      asm volatile("s_waitcnt lgkmcnt(0)" ::: "memory");
      __builtin_amdgcn_s_barrier();
      __builtin_amdgcn_sched_barrier(0);
      {
        const uint4* mp = mrow + (kt + 1) * 4 + kh * 2;
        asm volatile("global_load_dwordx4 %0, %2, off\n\t"
                     "global_load_dwordx4 %1, %3, off"
                     : "=&v"(mq0), "=&v"(mq1)
                     : "v"(mp), "v"(mp + 1)
                     : "memory");
      }
      if (kt < N_KT - 2) {
        const u32* g = img + (size_t)(kt + 2) * (TILE_SEGS * SEG_U32);
#pragma unroll
        for (int s = 0; s < 5; ++s)
          dma16(g + (size_t)(seg0 + s) * SEG_U32 + lane * 4,
                (u32*)&sbuf[p][0] + (seg0 + s) * SEG_U32);
      }
    }
  }

  // ---- cross-wave key-half reduction via LDS alias over sbuf[0] ----
  __syncthreads();  // tile31 lived in sbuf[1]; sbuf[0] is free to alias
  {
    float* xb = (float*)&sbuf[0][0];                     // 17408 B
    float* lb = (float*)((char*)&sbuf[0][0] + 17408);    // 256 B
    const float lsum = lacc0 + lacc1;
    const float l2 = lsum + __shfl_xor(lsum, 32);
    float* xr = xb + (size_t)(qh * 32 + col) * 68;
    if (kh) {
#pragma unroll
      for (int rg = 0; rg < 4; ++rg) {
        float4 w0, w1;
        w0.x = oT0[rg * 4 + 0]; w0.y = oT0[rg * 4 + 1];
        w0.z = oT0[rg * 4 + 2]; w0.w = oT0[rg * 4 + 3];
        w1.x = oT1[rg * 4 + 0]; w1.y = oT1[rg * 4 + 1];
        w1.z = oT1[rg * 4 + 2]; w1.w = oT1[rg * 4 + 3];
        *(float4*)(xr + 8 * rg + 4 * hl) = w0;
        *(float4*)(xr + 32 + 8 * rg + 4 * hl) = w1;
      }
      if (!hl) lb[qh * 32 + col] = l2;
    }
    __syncthreads();
    if (!kh) {
      const float inv = 1.0f / (l2 + lb[qh * 32 + col]);
      float* orow = out + hoff + (size_t)qg * D_DIM;
#pragma unroll
      for (int rg = 0; rg < 4; ++rg) {
        const float4 a0 = *(const float4*)(xr + 8 * rg + 4 * hl);
        const float4 a1 = *(const float4*)(xr + 32 + 8 * rg + 4 * hl);
        float4 w0, w1;
        w0.x = (oT0[rg * 4 + 0] + a0.x) * inv;
        w0.y = (oT0[rg * 4 + 1] + a0.y) * inv;
        w0.z = (oT0[rg * 4 + 2] + a0.z) * inv;
        w0.w = (oT0[rg * 4 + 3] + a0.w) * inv;
        w1.x = (oT1[rg * 4 + 0] + a1.x) * inv;
        w1.y = (oT1[rg * 4 + 1] + a1.y) * inv;
        w1.z = (oT1[rg * 4 + 2] + a1.z) * inv;
        w1.w = (oT1[rg * 4 + 3] + a1.w) * inv;
        *(float4*)(orow + 8 * rg + 4 * hl) = w0;
        *(float4*)(orow + 32 + 8 * rg + 4 * hl) = w1;
      }
    }
  }
}

// ---- fallback (round-4 kernel, self-staging) if ws is too small ----
#define LDK 72
#define LDV 72
__global__ __launch_bounds__(256, 2) void attn_fwd_self(
    const float* __restrict__ q, const float* __restrict__ k,
    const float* __restrict__ v, const int* __restrict__ mask,
    float* __restrict__ out) {
  const int qt = blockIdx.x;
  const int bh = blockIdx.y;
  const size_t hoff = (size_t)bh * (S_LEN * D_DIM);
  __shared__ unsigned short Ks[64 * LDK];
  __shared__ unsigned short Vt[64 * LDV];
  const int t = threadIdx.x;
  const int wave = t >> 6;
  const int lane = t & 63;
  const int col = lane & 31;
  const int hl = lane >> 5;
  const int sw = col >> 2;
  const int qg = qt * 128 + wave * 32 + col;
  bf16x8 bQ[4];
  {
    const float* qrow = q + hoff + (size_t)qg * D_DIM;
#pragma unroll
    for (int ks = 0; ks < 4; ++ks) {
      const float4 x0 = *(const float4*)(qrow + ks * 16 + hl * 8);
      const float4 x1 = *(const float4*)(qrow + ks * 16 + hl * 8 + 4);
      union { bf16x8 v; unsigned d[4]; } u;
      u.d[0] = packbf(x0.x, x0.y);
      u.d[1] = packbf(x0.z, x0.w);
      u.d[2] = packbf(x1.x, x1.y);
      u.d[3] = packbf(x1.z, x1.w);
      bQ[ks] = u.v;
    }
  }
  float4 pk[4], pv[4];
  {
    const float4* kg = (const float4*)(k + hoff);
    const float4* vg = (const float4*)(v + hoff);
#pragma unroll
    for (int j = 0; j < 4; ++j) { pk[j] = kg[t + j * 256]; pv[j] = vg[t + j * 256]; }
  }
  f32x16 oT0 = zero16(), oT1 = zero16();
  float lacc = 0.f;
  const int* mrow = mask + (size_t)qg * S_LEN;
  for (int kt = 0; kt < N_KT; ++kt) {
    __syncthreads();
#pragma unroll
    for (int j = 0; j < 4; ++j) {
      const int i = t + j * 256;
      const int row = i >> 4, c4 = i & 15;
      ushort4 w;
      w.x = f2bf(pk[j].x); w.y = f2bf(pk[j].y);
      w.z = f2bf(pk[j].z); w.w = f2bf(pk[j].w);
      *(ushort4*)&Ks[row * LDK + c4 * 4] = w;
      const int swc = 8 * (((row >> 3) + c4) & 7) + (row & 7);
      Vt[(4 * c4 + 0) * LDV + swc] = f2bf(pv[j].x);
      Vt[(4 * c4 + 1) * LDV + swc] = f2bf(pv[j].y);
      Vt[(4 * c4 + 2) * LDV + swc] = f2bf(pv[j].z);
      Vt[(4 * c4 + 3) * LDV + swc] = f2bf(pv[j].w);
    }
    __syncthreads();
    if (kt + 1 < N_KT) {
      const float4* kg = (const float4*)(k + hoff + (size_t)(kt + 1) * 64 * D_DIM);
      const float4* vg = (const float4*)(v + hoff + (size_t)(kt + 1) * 64 * D_DIM);
#pragma unroll
      for (int j = 0; j < 4; ++j) { pk[j] = kg[t + j * 256]; pv[j] = vg[t + j * 256]; }
    }
    int4 mq[2][4];
#pragma unroll
    for (int kb = 0; kb < 2; ++kb)
#pragma unroll
      for (int g = 0; g < 4; ++g)
        mq[kb][g] = *(const int4*)(mrow + kt * 64 + kb * 32 + g * 8 + hl * 4);
    f32x16 sT0 = zero16(), sT1 = zero16();
#pragma unroll
    for (int ks = 0; ks < 4; ++ks) {
      const bf16x8 aK0 = *(const bf16x8*)&Ks[col * LDK + ks * 16 + hl * 8];
      const bf16x8 aK1 = *(const bf16x8*)&Ks[(32 + col) * LDK + ks * 16 + hl * 8];
      sT0 = __builtin_amdgcn_mfma_f32_32x32x16_bf16(aK0, bQ[ks], sT0, 0, 0, 0);
      sT1 = __builtin_amdgcn_mfma_f32_32x32x16_bf16(aK1, bQ[ks], sT1, 0, 0, 0);
    }
    unsigned pw[2][8];
#pragma unroll
    for (int kb = 0; kb < 2; ++kb) {
      const f32x16 sT = kb ? sT1 : sT0;
      float e[16];
#pragma unroll
      for (int g = 0; g < 4; ++g) {
        const int4 mv = mq[kb][g];
        const int* mvp = &mv.x;
#pragma unroll
        for (int r3 = 0; r3 < 4; ++r3) {
          const int reg = g * 4 + r3;
          const float bias = mvp[r3] ? CM : 0.0f;
          const float ev = __builtin_amdgcn_exp2f(fmaf(sT[reg], C1, bias));
          e[reg] = ev;
          lacc += ev;
        }
        pw[kb][g * 2 + 0] = packbf(e[g * 4 + 0], e[g * 4 + 1]);
        pw[kb][g * 2 + 1] = packbf(e[g * 4 + 2], e[g * 4 + 3]);
      }
    }
#pragma unroll
    for (int ks = 0; ks < 4; ++ks) {
      const int kb = ks >> 1, h = ks & 1;
      const unsigned d0 = pw[kb][4 * h + 0], d1 = pw[kb][4 * h + 1];
      const unsigned d2 = pw[kb][4 * h + 2], d3 = pw[kb][4 * h + 3];
      const unsigned s0 = hl ? d0 : d2;
      const unsigned s1 = hl ? d1 : d3;
      const unsigned r0 = (unsigned)__shfl_xor((int)s0, 32);
      const unsigned r1 = (unsigned)__shfl_xor((int)s1, 32);
      union { bf16x8 v; unsigned d[4]; } pf;
      pf.d[0] = hl ? r0 : d0;
      pf.d[1] = hl ? r1 : d1;
      pf.d[2] = hl ? d2 : r0;
      pf.d[3] = hl ? d3 : r1;
      const int cpr = 8 * (((2 * ks + hl) + sw) & 7);
      const bf16x8 aV0 = *(const bf16x8*)&Vt[col * LDV + cpr];
      const bf16x8 aV1 = *(const bf16x8*)&Vt[(32 + col) * LDV + cpr];
      oT0 = __builtin_amdgcn_mfma_f32_32x32x16_bf16(aV0, pf.v, oT0, 0, 0, 0);
      oT1 = __builtin_amdgcn_mfma_f32_32x32x16_bf16(aV1, pf.v, oT1, 0, 0, 0);
    }
  }
  const float ltot = lacc + __shfl_xor(lacc, 32);
  const float inv = 1.0f / ltot;
  float* orow = out + hoff + (size_t)qg * D_DIM;
#pragma unroll
  for (int rg = 0; rg < 4; ++rg) {
    float4 w0, w1;
    w0.x = oT0[rg * 4 + 0] * inv; w0.y = oT0[rg * 4 + 1] * inv;
    w0.z = oT0[rg * 4 + 2] * inv; w0.w = oT0[rg * 4 + 3] * inv;
    w1.x = oT1[rg * 4 + 0] * inv; w1.y = oT1[rg * 4 + 1] * inv;
    w1.z = oT1[rg * 4 + 2] * inv; w1.w = oT1[rg * 4 + 3] * inv;
    *(float4*)(orow + 8 * rg + 4 * hl) = w0;
    *(float4*)(orow + 32 + 8 * rg + 4 * hl) = w1;
  }
}

extern "C" void kernel_launch(void* const* d_in, const int* in_sizes, int n_in,
                              void* d_out, int out_size, void* d_ws, size_t ws_size,
                              hipStream_t stream) {
  const float* q = (const float*)d_in[0];
  const float* k = (const float*)d_in[1];
  const float* v = (const float*)d_in[2];
  const int* mask = (const int*)d_in[3];
  float* out = (float*)d_out;

  const size_t kv_shorts = (size_t)NBH * N_KT * TILE_SHORTS_P;
  const size_t mw_words = (size_t)S_LEN * 2 * N_KT * 16;  // u32 count
  const size_t need = kv_shorts * sizeof(unsigned short) + mw_words * 4;

  if (ws_size >= need) {
    unsigned short* kvws = (unsigned short*)d_ws;
    u32* mwp = (u32*)(kvws + kv_shorts);
    prep_kv<<<dim3(N_KT, NBH), dim3(256), 0, stream>>>(k, v, kvws);
    prep_mask<<<dim3((S_LEN * 2 * N_KT * 4) / 256), dim3(256), 0, stream>>>(mask, mwp);
    attn_fwd<<<dim3(S_LEN / 64, NBH), dim3(256), 0, stream>>>(q, kvws, mwp, out);
  } else {
    attn_fwd_self<<<dim3(S_LEN / 128, NBH), dim3(256), 0, stream>>>(q, k, v, mask, out);
  }
}

// Round 10
// 163.873 us; speedup vs baseline: 1.6084x; 1.0207x over previous
//
#include <hip/hip_runtime.h>

// BaseAttention: B=2 H=16 S=2048 D=64, fp32 in/out.
// Round 14: frag-ordered image + counted-vmcnt pipeline + fused prep.
//   r13 post-mortem: counted vmcnt == r8 drain (77 vs 75.7us) => the drain was
//   never the bottleneck. Remaining measured waste: (1) 3.1M bank-conflict
//   cycles -- pitch-72 reads are 4-way conflicted (col*144B -> bank 4col%32);
//   frag-ordered layout (r10/r12-validated) reads 1KB contiguous per wave =
//   conflict-free, and image shrinks 20->16KB (FETCH -12%). (2) total-attn
//   ~= 89-90us constant across 4 prep variants => fuse prep_mask into prep_kv
//   (one fewer dispatch).
//   Pipeline (r13-validated): raw s_barrier + counted s_waitcnt vmcnt(4)
//   (never 0 mid-loop); 16 segs/tile, 4 segs/wave; masks via pinned inline-asm
//   dwordx4 issued BEFORE the stage cluster; per-iter vmem order
//   [ml(kt+1) x2, stage(kt+2) x4]; sched_barrier(0) after every fence.
//   Carried (HW-validated): kh-split 4-wave blocks; frag image [K 4096|V 4096]
//   shorts (r12); prep_mask AND-words (r12); fdot2 l; Q pre-scaled
//   0.125*log2e; P packed f16 pkrtz; PV mfma_32x32x16_f16; cross-wave reduce
//   via LDS alias at end.

#define S_LEN 2048
#define D_DIM 64
#define N_KT 32
#define NBH 32
#define TILE_SEGS 16
#define TILE_SHORTS 8192                 // 16 KB: [K frags 4096][V frags 4096]
#define SEG_U32 256                      // 1024 B per seg (64 lanes x 16 B)

typedef __attribute__((ext_vector_type(8))) short bf16x8;
typedef __attribute__((ext_vector_type(16))) float f32x16;
typedef __attribute__((ext_vector_type(2))) __fp16 fp16x2;
typedef unsigned int u32;

#define C1 0.180336880111121f    // 0.125 * log2(e)
#define CM (-14426.9504088896f)  // -10000 * log2(e)  (fallback kernel only)

static __device__ __forceinline__ unsigned short f2bf(float f) {
  union { float f; unsigned u; } x; x.f = f;
  return (unsigned short)((x.u + 0x8000u) >> 16);
}
static __device__ __forceinline__ unsigned packbf(float lo, float hi) {
  union { float f; unsigned u; } a, b; a.f = lo; b.f = hi;
  return ((a.u + 0x8000u) >> 16) | ((b.u + 0x8000u) & 0xffff0000u);
}
static __device__ __forceinline__ f32x16 zero16() {
  f32x16 z;
#pragma unroll
  for (int i = 0; i < 16; ++i) z[i] = 0.f;
  return z;
}
static __device__ __forceinline__ void dma16(const u32* g, u32* l) {
  __builtin_amdgcn_global_load_lds(
      (const __attribute__((address_space(1))) u32*)g,
      (__attribute__((address_space(3))) u32*)l, 16, 0, 0);
}
static __device__ __forceinline__ unsigned pkh(float lo, float hi) {
  union { fp16x2 h; unsigned u; } x;
  x.h = __builtin_amdgcn_cvt_pkrtz(lo, hi);
  return x.u;
}

// ---- fused pre-pass: blocks [0,1024): K,V frag image; [1024,3072): mask ----
// KV image per (bh,kt), 8192 shorts (r12-validated layout):
//   [0..4095]  K frags [kh(2)][ks(4)][hl(2)][col(32)][8]:
//              bf16( K[key=kh*32+col][d=ks*16+hl*8+j] )
//   [4096..]   V frags [kcHi(4)][hl(2)][b(2)][col(32)][8]:
//              f16( V[key=(2*kcHi+hl)*8+j][d=b*32+col] )
// Mask words (r12-validated): word p=kb*8+g*2+h of (row,hl,kt) covers keys
//   j=32kb+8g+4hl+2h+{0,1}; mask==0 -> keep (0xFFFF).
__global__ __launch_bounds__(256) void prep_fused(
    const float* __restrict__ k, const float* __restrict__ v,
    const int* __restrict__ mask, unsigned short* __restrict__ kvws,
    u32* __restrict__ mw) {
  __shared__ unsigned short Kr[64 * 72];
  __shared__ unsigned short Vr[64 * 72];
  const int blk = blockIdx.x;
  const int t = threadIdx.x;
  if (blk < N_KT * NBH) {
    const int kt = blk & 31, bh = blk >> 5;
    const size_t goff = (size_t)bh * (S_LEN * D_DIM) + (size_t)kt * 64 * D_DIM;
    const float4* kg = (const float4*)(k + goff);
    const float4* vg = (const float4*)(v + goff);
#pragma unroll
    for (int j = 0; j < 4; ++j) {
      const int i = t + j * 256;
      const int row = i >> 4, c4 = i & 15;  // row = key, c4 = d-group
      const float4 x = kg[i];
      ushort4 w;
      w.x = f2bf(x.x); w.y = f2bf(x.y); w.z = f2bf(x.z); w.w = f2bf(x.w);
      *(ushort4*)&Kr[row * 72 + c4 * 4] = w;
      const float4 y = vg[i];
      const unsigned p01 = pkh(y.x, y.y), p23 = pkh(y.z, y.w);
      uint2 vv; vv.x = p01; vv.y = p23;
      *(uint2*)&Vr[row * 72 + c4 * 4] = vv;
    }
    __syncthreads();
    uint4* img = (uint4*)(kvws + (size_t)(bh * N_KT + kt) * TILE_SHORTS);
    // K frags: 512 x 16B
    for (int c = t; c < 512; c += 256) {
      const int col = c & 31, hlc = (c >> 5) & 1, ks = (c >> 6) & 3, khc = c >> 8;
      img[c] = *(const uint4*)&Kr[(khc * 32 + col) * 72 + ks * 16 + hlc * 8];
    }
    // V frags (transpose gather): 512 x 16B at +512
    for (int c = t; c < 512; c += 256) {
      const int col = c & 31, b = (c >> 5) & 1, hlc = (c >> 6) & 1, kcHi = c >> 7;
      const int d = b * 32 + col, kk = (2 * kcHi + hlc) * 8;
      union { unsigned short s[8]; uint4 u; } o;
#pragma unroll
      for (int jj = 0; jj < 8; ++jj) o.s[jj] = Vr[(kk + jj) * 72 + d];
      img[512 + c] = o.u;
    }
  } else {
    const int gt = (blk - N_KT * NBH) * 256 + t;  // 524288 total
    const int q4 = gt & 3;
    const int kt = (gt >> 2) & 31;
    const int hl = (gt >> 7) & 1;
    const int row = gt >> 8;
    const int j0 = kt * 64 + 32 * (q4 >> 1) + 16 * (q4 & 1) + 4 * hl;
    const int* mr = mask + (size_t)row * S_LEN;
    const int4 a = *(const int4*)(mr + j0);
    const int4 b = *(const int4*)(mr + j0 + 8);
    uint4 w;
    w.x = (a.x == 0 ? 0x0000FFFFu : 0u) | (a.y == 0 ? 0xFFFF0000u : 0u);
    w.y = (a.z == 0 ? 0x0000FFFFu : 0u) | (a.w == 0 ? 0xFFFF0000u : 0u);
    w.z = (b.x == 0 ? 0x0000FFFFu : 0u) | (b.y == 0 ? 0xFFFF0000u : 0u);
    w.w = (b.z == 0 ? 0x0000FFFFu : 0u) | (b.w == 0 ? 0xFFFF0000u : 0u);
    *(uint4*)&mw[((size_t)(row * 2 + hl) * N_KT + kt) * 16 + q4 * 4] = w;
  }
}

// ---- main: flash attention, counted-vmcnt DMA pipeline, frag-ordered LDS ----
__global__ __launch_bounds__(256, 4) void attn_fwd(
    const float* __restrict__ q, const unsigned short* __restrict__ kvws,
    const u32* __restrict__ mw, float* __restrict__ out) {
  const int qt = blockIdx.x;  // 0..31 (64 q rows per block)
  const int bh = blockIdx.y;  // 0..31
  const size_t hoff = (size_t)bh * (S_LEN * D_DIM);

  __shared__ unsigned short sbuf[2][TILE_SHORTS];  // 2 x 16 KB

  const int t = threadIdx.x;
  const int wave = t >> 6;
  const int lane = t & 63;
  const int col = lane & 31;
  const int hl = lane >> 5;
  const int qh = wave >> 1;  // q half
  const int kh = wave & 1;   // key half of each tile
  const int qg = qt * 64 + qh * 32 + col;

  // Q^T B-fragments, PRE-SCALED by C1
  bf16x8 bQ[4];
  {
    const float* qrow = q + hoff + (size_t)qg * D_DIM;
#pragma unroll
    for (int ks = 0; ks < 4; ++ks) {
      const float4 x0 = *(const float4*)(qrow + ks * 16 + hl * 8);
      const float4 x1 = *(const float4*)(qrow + ks * 16 + hl * 8 + 4);
      union { bf16x8 v; unsigned d[4]; } u;
      u.d[0] = packbf(x0.x * C1, x0.y * C1);
      u.d[1] = packbf(x0.z * C1, x0.w * C1);
      u.d[2] = packbf(x1.x * C1, x1.y * C1);
      u.d[3] = packbf(x1.z * C1, x1.w * C1);
      bQ[ks] = u.v;
    }
  }

  f32x16 oT0 = zero16(), oT1 = zero16();
  float lacc0 = 0.f, lacc1 = 0.f;
  const uint4* mrow = (const uint4*)(mw + (size_t)(qg * 2 + hl) * N_KT * 16);
  const u32* img = (const u32*)(kvws + (size_t)bh * N_KT * TILE_SHORTS);
  const int seg0 = wave * 4;  // this wave's 4 segments of each 16-seg tile

#if __has_builtin(__builtin_amdgcn_fdot2)
  const fp16x2 ones2 = {(__fp16)1.0f, (__fp16)1.0f};
#endif

  uint4 mq0, mq1;
  // prologue vmem order (per wave): ml(0) x2, stage(0) x4, stage(1) x4.
  {
    const uint4* mp = mrow + kh * 2;
    asm volatile("global_load_dwordx4 %0, %2, off\n\t"
                 "global_load_dwordx4 %1, %3, off"
                 : "=&v"(mq0), "=&v"(mq1)
                 : "v"(mp), "v"(mp + 1)
                 : "memory");
  }
#pragma unroll
  for (int s = 0; s < 4; ++s)
    dma16(img + (size_t)(seg0 + s) * SEG_U32 + lane * 4,
          (u32*)&sbuf[0][0] + (seg0 + s) * SEG_U32);
#pragma unroll
  for (int s = 0; s < 4; ++s)
    dma16(img + (size_t)(TILE_SEGS + seg0 + s) * SEG_U32 + lane * 4,
          (u32*)&sbuf[1][0] + (seg0 + s) * SEG_U32);

  for (int kt = 0; kt < N_KT; ++kt) {
    const int p = kt & 1;
    // entry: wait own-wave DMAs for tile kt (+ mask kt); tile kt+1 in flight
    if (kt < N_KT - 1) {
      asm volatile("s_waitcnt vmcnt(4)" ::: "memory");
    } else {
      asm volatile("s_waitcnt vmcnt(0)" ::: "memory");
    }
    __builtin_amdgcn_s_barrier();
    __builtin_amdgcn_sched_barrier(0);

    const unsigned short* Ksb = &sbuf[p][0];
    const unsigned short* Vtb = &sbuf[p][4096];
    const u32 mwv[8] = {mq0.x, mq0.y, mq0.z, mq0.w,
                        mq1.x, mq1.y, mq1.z, mq1.w};

    // S^T = K Q^T : this wave's 32-key half x K=64 (pre-scaled via Q)
    // frag-ordered K: 64 lanes read 1KB contiguous => conflict-free
    f32x16 sT = zero16();
#pragma unroll
    for (int ks = 0; ks < 4; ++ks) {
      const bf16x8 aK =
          *(const bf16x8*)&Ksb[kh * 2048 + ks * 512 + hl * 256 + col * 8];
      sT = __builtin_amdgcn_mfma_f32_32x32x16_bf16(aK, bQ[ks], sT, 0, 0, 0);
    }

    // p = exp2(s), pack f16 (pkrtz), mask with AND-words, l via fdot2
    unsigned pw[8];
#pragma unroll
    for (int g2 = 0; g2 < 4; ++g2) {
      const float e0 = __builtin_amdgcn_exp2f(sT[g2 * 4 + 0]);
      const float e1 = __builtin_amdgcn_exp2f(sT[g2 * 4 + 1]);
      const float e2 = __builtin_amdgcn_exp2f(sT[g2 * 4 + 2]);
      const float e3 = __builtin_amdgcn_exp2f(sT[g2 * 4 + 3]);
#if __has_builtin(__builtin_amdgcn_fdot2)
      const unsigned w0 = pkh(e0, e1) & mwv[g2 * 2 + 0];
      const unsigned w1 = pkh(e2, e3) & mwv[g2 * 2 + 1];
      pw[g2 * 2 + 0] = w0;
      pw[g2 * 2 + 1] = w1;
      union { unsigned u; fp16x2 h; } c0, c1;
      c0.u = w0; c1.u = w1;
      lacc0 = __builtin_amdgcn_fdot2(c0.h, ones2, lacc0, false);
      lacc1 = __builtin_amdgcn_fdot2(c1.h, ones2, lacc1, false);
#else
      const u32 mlo = mwv[g2 * 2 + 0], mhi = mwv[g2 * 2 + 1];
      const float e0m = (mlo & 0xFFFFu) ? e0 : 0.f;
      const float e1m = (mlo >> 16) ? e1 : 0.f;
      const float e2m = (mhi & 0xFFFFu) ? e2 : 0.f;
      const float e3m = (mhi >> 16) ? e3 : 0.f;
      pw[g2 * 2 + 0] = pkh(e0m, e1m);
      pw[g2 * 2 + 1] = pkh(e2m, e3m);
      lacc0 += e0m + e1m;
      lacc1 += e2m + e3m;
#endif
    }

    // O^T += Vt * P^T (frag-ordered V: contiguous 16B/lane reads)
#pragma unroll
    for (int ks2 = 0; ks2 < 2; ++ks2) {
      const unsigned d0 = pw[4 * ks2 + 0], d1 = pw[4 * ks2 + 1];
      const unsigned d2 = pw[4 * ks2 + 2], d3 = pw[4 * ks2 + 3];
      const unsigned s0 = hl ? d0 : d2;
      const unsigned s1 = hl ? d1 : d3;
      const unsigned r0 = (unsigned)__shfl_xor((int)s0, 32);
      const unsigned r1 = (unsigned)__shfl_xor((int)s1, 32);
      union { bf16x8 v; unsigned d[4]; } pf;
      pf.d[0] = hl ? r0 : d0;
      pf.d[1] = hl ? r1 : d1;
      pf.d[2] = hl ? d2 : r0;
      pf.d[3] = hl ? d3 : r1;
      const int kcHi = kh * 2 + ks2;
      const bf16x8 aV0 =
          *(const bf16x8*)&Vtb[kcHi * 1024 + hl * 512 + 0 * 256 + col * 8];
      const bf16x8 aV1 =
          *(const bf16x8*)&Vtb[kcHi * 1024 + hl * 512 + 1 * 256 + col * 8];
      oT0 = __builtin_amdgcn_mfma_f32_32x32x16_f16(aV0, pf.v, oT0, 0, 0, 0);
      oT1 = __builtin_amdgcn_mfma_f32_32x32x16_f16(aV1, pf.v, oT1, 0, 0, 0);
    }

    // exit: reads of buf[p] done -> allow re-staging it; masks BEFORE dmas
    if (kt < N_KT - 1) {
      asm volatile("s_waitcnt lgkmcnt(0)" ::: "memory");
      __builtin_amdgcn_s_barrier();
      __builtin_amdgcn_sched_barrier(0);
      {
        const uint4* mp = mrow + (kt + 1) * 4 + kh * 2;
        asm volatile("global_load_dwordx4 %0, %2, off\n\t"
                     "global_load_dwordx4 %1, %3, off"
                     : "=&v"(mq0), "=&v"(mq1)
                     : "v"(mp), "v"(mp + 1)
                     : "memory");
      }
      if (kt < N_KT - 2) {
        const u32* g = img + (size_t)(kt + 2) * (TILE_SEGS * SEG_U32);
#pragma unroll
        for (int s = 0; s < 4; ++s)
          dma16(g + (size_t)(seg0 + s) * SEG_U32 + lane * 4,
                (u32*)&sbuf[p][0] + (seg0 + s) * SEG_U32);
      }
    }
  }

  // ---- cross-wave key-half reduction via LDS alias over sbuf ----
  __syncthreads();  // all tile reads done; sbuf free to alias (17664B used)
  {
    float* xb = (float*)&sbuf[0][0];                     // 17408 B
    float* lb = (float*)((char*)&sbuf[0][0] + 17408);    // 256 B
    const float lsum = lacc0 + lacc1;
    const float l2 = lsum + __shfl_xor(lsum, 32);
    float* xr = xb + (size_t)(qh * 32 + col) * 68;
    if (kh) {
#pragma unroll
      for (int rg = 0; rg < 4; ++rg) {
        float4 w0, w1;
        w0.x = oT0[rg * 4 + 0]; w0.y = oT0[rg * 4 + 1];
        w0.z = oT0[rg * 4 + 2]; w0.w = oT0[rg * 4 + 3];
        w1.x = oT1[rg * 4 + 0]; w1.y = oT1[rg * 4 + 1];
        w1.z = oT1[rg * 4 + 2]; w1.w = oT1[rg * 4 + 3];
        *(float4*)(xr + 8 * rg + 4 * hl) = w0;
        *(float4*)(xr + 32 + 8 * rg + 4 * hl) = w1;
      }
      if (!hl) lb[qh * 32 + col] = l2;
    }
    __syncthreads();
    if (!kh) {
      const float inv = 1.0f / (l2 + lb[qh * 32 + col]);
      float* orow = out + hoff + (size_t)qg * D_DIM;
#pragma unroll
      for (int rg = 0; rg < 4; ++rg) {
        const float4 a0 = *(const float4*)(xr + 8 * rg + 4 * hl);
        const float4 a1 = *(const float4*)(xr + 32 + 8 * rg + 4 * hl);
        float4 w0, w1;
        w0.x = (oT0[rg * 4 + 0] + a0.x) * inv;
        w0.y = (oT0[rg * 4 + 1] + a0.y) * inv;
        w0.z = (oT0[rg * 4 + 2] + a0.z) * inv;
        w0.w = (oT0[rg * 4 + 3] + a0.w) * inv;
        w1.x = (oT1[rg * 4 + 0] + a1.x) * inv;
        w1.y = (oT1[rg * 4 + 1] + a1.y) * inv;
        w1.z = (oT1[rg * 4 + 2] + a1.z) * inv;
        w1.w = (oT1[rg * 4 + 3] + a1.w) * inv;
        *(float4*)(orow + 8 * rg + 4 * hl) = w0;
        *(float4*)(orow + 32 + 8 * rg + 4 * hl) = w1;
      }
    }
  }
}

// ---- fallback (round-4 kernel, self-staging) if ws is too small ----
#define LDK 72
#define LDV 72
__global__ __launch_bounds__(256, 2) void attn_fwd_self(
    const float* __restrict__ q, const float* __restrict__ k,
    const float* __restrict__ v, const int* __restrict__ mask,
    float* __restrict__ out) {
  const int qt = blockIdx.x;
  const int bh = blockIdx.y;
  const size_t hoff = (size_t)bh * (S_LEN * D_DIM);
  __shared__ unsigned short Ks[64 * LDK];
  __shared__ unsigned short Vt[64 * LDV];
  const int t = threadIdx.x;
  const int wave = t >> 6;
  const int lane = t & 63;
  const int col = lane & 31;
  const int hl = lane >> 5;
  const int sw = col >> 2;
  const int qg = qt * 128 + wave * 32 + col;
  bf16x8 bQ[4];
  {
    const float* qrow = q + hoff + (size_t)qg * D_DIM;
#pragma unroll
    for (int ks = 0; ks < 4; ++ks) {
      const float4 x0 = *(const float4*)(qrow + ks * 16 + hl * 8);
      const float4 x1 = *(const float4*)(qrow + ks * 16 + hl * 8 + 4);
      union { bf16x8 v; unsigned d[4]; } u;
      u.d[0] = packbf(x0.x, x0.y);
      u.d[1] = packbf(x0.z, x0.w);
      u.d[2] = packbf(x1.x, x1.y);
      u.d[3] = packbf(x1.z, x1.w);
      bQ[ks] = u.v;
    }
  }
  float4 pk[4], pv[4];
  {
    const float4* kg = (const float4*)(k + hoff);
    const float4* vg = (const float4*)(v + hoff);
#pragma unroll
    for (int j = 0; j < 4; ++j) { pk[j] = kg[t + j * 256]; pv[j] = vg[t + j * 256]; }
  }
  f32x16 oT0 = zero16(), oT1 = zero16();
  float lacc = 0.f;
  const int* mrow = mask + (size_t)qg * S_LEN;
  for (int kt = 0; kt < N_KT; ++kt) {
    __syncthreads();
#pragma unroll
    for (int j = 0; j < 4; ++j) {
      const int i = t + j * 256;
      const int row = i >> 4, c4 = i & 15;
      ushort4 w;
      w.x = f2bf(pk[j].x); w.y = f2bf(pk[j].y);
      w.z = f2bf(pk[j].z); w.w = f2bf(pk[j].w);
      *(ushort4*)&Ks[row * LDK + c4 * 4] = w;
      const int swc = 8 * (((row >> 3) + c4) & 7) + (row & 7);
      Vt[(4 * c4 + 0) * LDV + swc] = f2bf(pv[j].x);
      Vt[(4 * c4 + 1) * LDV + swc] = f2bf(pv[j].y);
      Vt[(4 * c4 + 2) * LDV + swc] = f2bf(pv[j].z);
      Vt[(4 * c4 + 3) * LDV + swc] = f2bf(pv[j].w);
    }
    __syncthreads();
    if (kt + 1 < N_KT) {
      const float4* kg = (const float4*)(k + hoff + (size_t)(kt + 1) * 64 * D_DIM);
      const float4* vg = (const float4*)(v + hoff + (size_t)(kt + 1) * 64 * D_DIM);
#pragma unroll
      for (int j = 0; j < 4; ++j) { pk[j] = kg[t + j * 256]; pv[j] = vg[t + j * 256]; }
    }
    int4 mq[2][4];
#pragma unroll
    for (int kb = 0; kb < 2; ++kb)
#pragma unroll
      for (int g = 0; g < 4; ++g)
        mq[kb][g] = *(const int4*)(mrow + kt * 64 + kb * 32 + g * 8 + hl * 4);
    f32x16 sT0 = zero16(), sT1 = zero16();
#pragma unroll
    for (int ks = 0; ks < 4; ++ks) {
      const bf16x8 aK0 = *(const bf16x8*)&Ks[col * LDK + ks * 16 + hl * 8];
      const bf16x8 aK1 = *(const bf16x8*)&Ks[(32 + col) * LDK + ks * 16 + hl * 8];
      sT0 = __builtin_amdgcn_mfma_f32_32x32x16_bf16(aK0, bQ[ks], sT0, 0, 0, 0);
      sT1 = __builtin_amdgcn_mfma_f32_32x32x16_bf16(aK1, bQ[ks], sT1, 0, 0, 0);
    }
    unsigned pw[2][8];
#pragma unroll
    for (int kb = 0; kb < 2; ++kb) {
      const f32x16 sT = kb ? sT1 : sT0;
      float e[16];
#pragma unroll
      for (int g = 0; g < 4; ++g) {
        const int4 mv = mq[kb][g];
        const int* mvp = &mv.x;
#pragma unroll
        for (int r3 = 0; r3 < 4; ++r3) {
          const int reg = g * 4 + r3;
          const float bias = mvp[r3] ? CM : 0.0f;
          const float ev = __builtin_amdgcn_exp2f(fmaf(sT[reg], C1, bias));
          e[reg] = ev;
          lacc += ev;
        }
        pw[kb][g * 2 + 0] = packbf(e[g * 4 + 0], e[g * 4 + 1]);
        pw[kb][g * 2 + 1] = packbf(e[g * 4 + 2], e[g * 4 + 3]);
      }
    }
#pragma unroll
    for (int ks = 0; ks < 4; ++ks) {
      const int kb = ks >> 1, h = ks & 1;
      const unsigned d0 = pw[kb][4 * h + 0], d1 = pw[kb][4 * h + 1];
      const unsigned d2 = pw[kb][4 * h + 2], d3 = pw[kb][4 * h + 3];
      const unsigned s0 = hl ? d0 : d2;
      const unsigned s1 = hl ? d1 : d3;
      const unsigned r0 = (unsigned)__shfl_xor((int)s0, 32);
      const unsigned r1 = (unsigned)__shfl_xor((int)s1, 32);
      union { bf16x8 v; unsigned d[4]; } pf;
      pf.d[0] = hl ? r0 : d0;
      pf.d[1] = hl ? r1 : d1;
      pf.d[2] = hl ? d2 : r0;
      pf.d[3] = hl ? d3 : r1;
      const int cpr = 8 * (((2 * ks + hl) + sw) & 7);
      const bf16x8 aV0 = *(const bf16x8*)&Vt[col * LDV + cpr];
      const bf16x8 aV1 = *(const bf16x8*)&Vt[(32 + col) * LDV + cpr];
      oT0 = __builtin_amdgcn_mfma_f32_32x32x16_bf16(aV0, pf.v, oT0, 0, 0, 0);
      oT1 = __builtin_amdgcn_mfma_f32_32x32x16_bf16(aV1, pf.v, oT1, 0, 0, 0);
    }
  }
  const float ltot = lacc + __shfl_xor(lacc, 32);
  const float inv = 1.0f / ltot;
  float* orow = out + hoff + (size_t)qg * D_DIM;
#pragma unroll
  for (int rg = 0; rg < 4; ++rg) {
    float4 w0, w1;
    w0.x = oT0[rg * 4 + 0] * inv; w0.y = oT0[rg * 4 + 1] * inv;
    w0.z = oT0[rg * 4 + 2] * inv; w0.w = oT0[rg * 4 + 3] * inv;
    w1.x = oT1[rg * 4 + 0] * inv; w1.y = oT1[rg * 4 + 1] * inv;
    w1.z = oT1[rg * 4 + 2] * inv; w1.w = oT1[rg * 4 + 3] * inv;
    *(float4*)(orow + 8 * rg + 4 * hl) = w0;
    *(float4*)(orow + 32 + 8 * rg + 4 * hl) = w1;
  }
}

extern "C" void kernel_launch(void* const* d_in, const int* in_sizes, int n_in,
                              void* d_out, int out_size, void* d_ws, size_t ws_size,
                              hipStream_t stream) {
  const float* q = (const float*)d_in[0];
  const float* k = (const float*)d_in[1];
  const float* v = (const float*)d_in[2];
  const int* mask = (const int*)d_in[3];
  float* out = (float*)d_out;

  const size_t kv_shorts = (size_t)NBH * N_KT * TILE_SHORTS;
  const size_t mw_words = (size_t)S_LEN * 2 * N_KT * 16;  // u32 count
  const size_t need = kv_shorts * sizeof(unsigned short) + mw_words * 4;

  if (ws_size >= need) {
    unsigned short* kvws = (unsigned short*)d_ws;
    u32* mwp = (u32*)(kvws + kv_shorts);
    prep_fused<<<dim3(N_KT * NBH + (S_LEN * 2 * N_KT * 4) / 256), dim3(256), 0,
                 stream>>>(k, v, mask, kvws, mwp);
    attn_fwd<<<dim3(S_LEN / 64, NBH), dim3(256), 0, stream>>>(q, kvws, mwp, out);
  } else {
    attn_fwd_self<<<dim3(S_LEN / 128, NBH), dim3(256), 0, stream>>>(q, k, v, mask, out);
  }
}